// Round 8
// baseline (503.870 us; speedup 1.0000x reference)
//
#include <hip/hip_runtime.h>
#include <hip/hip_bf16.h>
#include <math.h>

#define FIN 256
#define F1  256   // H1*HID = 8*32
#define C2  16
#define NEG 0.2f

typedef short bf16x8 __attribute__((ext_vector_type(8)));
typedef float f32x4v __attribute__((ext_vector_type(4)));
typedef float f32x2 __attribute__((ext_vector_type(2)));

__device__ __forceinline__ float bf2f(unsigned short u) {
  union { float f; unsigned int i; } c; c.i = ((unsigned int)u) << 16; return c.f;
}
__device__ __forceinline__ unsigned short f2bf(float f) {
  __hip_bfloat16 b = __float2bfloat16(f);
  return *(unsigned short*)&b;
}
// two bf16 packed in a u32 -> two f32
__device__ __forceinline__ f32x2 bfpair(unsigned int u) {
  union { float f; unsigned int i; } lo, hi;
  lo.i = u << 16;
  hi.i = u & 0xffff0000u;
  f32x2 r; r.x = lo.f; r.y = hi.f; return r;
}

// ---------------- CSR build ----------------
__global__ __launch_bounds__(256) void deg_kernel(const int* __restrict__ dst,
                                                  int* __restrict__ deg, int E) {
  int e = blockIdx.x * blockDim.x + threadIdx.x;
  if (e < E) atomicAdd(&deg[dst[e]], 1);
}

__global__ __launch_bounds__(1024) void scan_part_kernel(const int* __restrict__ deg,
    int* __restrict__ offs, int* __restrict__ partials, int n) {
  __shared__ int wsum[16], wpref[16];
  int tid = threadIdx.x, lane = tid & 63, wid = tid >> 6;
  int idx = blockIdx.x * 1024 + tid;
  int v = (idx < n) ? deg[idx] : 0;
  int s = v;
#pragma unroll
  for (int o = 1; o < 64; o <<= 1) {
    int t = __shfl_up(s, o, 64);
    if (lane >= o) s += t;
  }
  if (lane == 63) wsum[wid] = s;
  __syncthreads();
  if (tid < 16) {
    int t = wsum[tid];
    int ss = t;
#pragma unroll
    for (int o = 1; o < 16; o <<= 1) {
      int u = __shfl_up(ss, o, 16);
      if (tid >= o) ss += u;
    }
    wpref[tid] = ss - t;
    if (tid == 15) partials[blockIdx.x] = ss;
  }
  __syncthreads();
  if (idx < n) offs[idx] = wpref[wid] + s - v;
}

// fused: re-scan partials in every block; block 0 writes total, blocks b>0 add carry
__global__ __launch_bounds__(1024) void scan_fix_kernel(int* __restrict__ offs,
    const int* __restrict__ partials, int nb, int n) {
  __shared__ int carry_s;
  int tid = threadIdx.x;
  int b = blockIdx.x;
  if (tid < 64) {
    int v = (tid < nb) ? partials[tid] : 0;
    int s = v;
#pragma unroll
    for (int o = 1; o < 64; o <<= 1) {
      int t = __shfl_up(s, o, 64);
      if (tid >= o) s += t;
    }
    if (b == 0) {
      if (tid == nb - 1) offs[n] = s;
    } else if (tid == b - 1) {
      carry_s = s;
    }
  }
  __syncthreads();
  if (b > 0) {
    int idx = b * 1024 + tid;
    if (idx < n) offs[idx] += carry_s;
  }
}

__global__ __launch_bounds__(256) void fill_kernel(const int* __restrict__ src,
    const int* __restrict__ dst, const int* __restrict__ offs,
    int* __restrict__ cnt, int* __restrict__ csr, int E) {
  int e = blockIdx.x * blockDim.x + threadIdx.x;
  if (e < E) {
    int d = dst[e];
    int pos = offs[d] + atomicAdd(&cnt[d], 1);
    csr[pos] = src[e];
  }
}

// ---------------- weight converts (tiny, once) ----------------
__global__ __launch_bounds__(256) void cvt_w_kernel(const float* __restrict__ Wl,
    const float* __restrict__ Wr, unsigned short* __restrict__ Wt) {
  int n = blockIdx.x;
  int k = threadIdx.x;
  float v = (n < 256) ? Wl[k * 256 + n] : Wr[k * 256 + (n - 256)];
  Wt[n * 256 + k] = f2bf(v);
}

__global__ __launch_bounds__(256) void cvt_w2_kernel(const float* __restrict__ Wl,
    const float* __restrict__ Wr, unsigned short* __restrict__ Wt2) {
  int c = blockIdx.x;
  int k = threadIdx.x;
  float v = (c < 16) ? Wl[k * 16 + c] : Wr[k * 16 + (c - 16)];
  Wt2[c * 256 + k] = f2bf(v);
}

// ---------------- MFMA GEMM: A in LDS (BK=128, fused f32->bf16), B streamed from L2 ----------------
// tile 128x128, 4 waves (2x2), XCD-bijective swizzle. Only 4 barriers per block.
#define LDA1 136
__global__ __launch_bounds__(256) void gemm_mfma_kernel(
    const float* __restrict__ A, const unsigned short* __restrict__ Bt,
    unsigned short* __restrict__ C, int M) {
  __shared__ __align__(16) unsigned short As[128 * LDA1];   // 34.8 KB
  int tid = threadIdx.x;
  int G = gridDim.x;
  int q = G >> 3, r = G & 7;
  int b = blockIdx.x;
  int xcd = b & 7, pos = b >> 3;
  int swz = (xcd < r) ? xcd * (q + 1) + pos : r * (q + 1) + (xcd - r) * q + pos;
  int row0 = (swz >> 2) * 128;
  int col0 = (swz & 3) * 128;
  int wid = tid >> 6, lane = tid & 63;
  int wr = wid >> 1, wc = wid & 1;
  int r16 = lane & 15, kb = (lane >> 4) * 8;

  f32x4v acc[4][4];
#pragma unroll
  for (int m = 0; m < 4; m++)
#pragma unroll
    for (int n = 0; n < 4; n++)
#pragma unroll
      for (int qq = 0; qq < 4; qq++) acc[m][n][qq] = 0.f;

  // B row base for this wave (per n: +16 rows)
  const unsigned short* Bw = Bt + (size_t)(col0 + wc * 64 + r16) * 256;

  for (int k0 = 0; k0 < 256; k0 += 128) {
    // stage A chunk: 128 rows x 128 cols, f32 -> bf16
#pragma unroll
    for (int it = 0; it < 8; it++) {
      int g = tid + it * 256;         // 0..2047 granules of 8 cols
      int rr = g >> 4;
      int c8 = (g & 15) * 8;
      int gr = row0 + rr;
      float4 a0 = make_float4(0.f, 0.f, 0.f, 0.f);
      float4 a1 = make_float4(0.f, 0.f, 0.f, 0.f);
      if (gr < M) {
        a0 = *(const float4*)&A[(size_t)gr * 256 + k0 + c8];
        a1 = *(const float4*)&A[(size_t)gr * 256 + k0 + c8 + 4];
      }
      ushort4 lo, hi;
      lo.x = f2bf(a0.x); lo.y = f2bf(a0.y); lo.z = f2bf(a0.z); lo.w = f2bf(a0.w);
      hi.x = f2bf(a1.x); hi.y = f2bf(a1.y); hi.z = f2bf(a1.z); hi.w = f2bf(a1.w);
      *(ushort4*)&As[rr * LDA1 + c8] = lo;
      *(ushort4*)&As[rr * LDA1 + c8 + 4] = hi;
    }
    __syncthreads();
    // compute: 4 kk-steps, B direct from global (L2-resident 256 KB)
#pragma unroll
    for (int kk = 0; kk < 128; kk += 32) {
      bf16x8 af[4], bfr[4];
#pragma unroll
      for (int n = 0; n < 4; n++)
        bfr[n] = *(const bf16x8*)&Bw[(size_t)(n * 16) * 256 + k0 + kk + kb];
#pragma unroll
      for (int m = 0; m < 4; m++)
        af[m] = *(const bf16x8*)&As[(wr * 64 + m * 16 + r16) * LDA1 + kk + kb];
#pragma unroll
      for (int m = 0; m < 4; m++)
#pragma unroll
        for (int n = 0; n < 4; n++)
          acc[m][n] = __builtin_amdgcn_mfma_f32_16x16x32_bf16(af[m], bfr[n], acc[m][n], 0, 0, 0);
    }
    __syncthreads();
  }
  int rq = (lane >> 4) * 4;
#pragma unroll
  for (int m = 0; m < 4; m++) {
#pragma unroll
    for (int n = 0; n < 4; n++) {
#pragma unroll
      for (int qq = 0; qq < 4; qq++) {
        int gr = row0 + wr * 64 + m * 16 + rq + qq;
        if (gr < M) {
          int gc = col0 + wc * 64 + n * 16 + r16;
          C[(size_t)gr * 512 + gc] = f2bf(acc[m][n][qq]);
        }
      }
    }
  }
}

// ---------------- layer-2 MFMA GEMM: C[M,32](bf16) = h[M,256](bf16) @ Wt2^T ----------------
#define LDT 72
#define LDB2 264
__global__ __launch_bounds__(256) void gemm2_mfma_kernel(
    const unsigned short* __restrict__ A, const unsigned short* __restrict__ Bt,
    unsigned short* __restrict__ C, int M) {
  __shared__ __align__(16) unsigned short As[256 * LDT];
  __shared__ __align__(16) unsigned short Bs[32 * LDB2];
  int tid = threadIdx.x;
  int row0 = blockIdx.x * 256;
  int wid = tid >> 6, lane = tid & 63;
  int r16 = lane & 15, kb = (lane >> 4) * 8, rq = (lane >> 4) * 4;

#pragma unroll
  for (int it = 0; it < 4; it++) {
    int g = tid + it * 256;
    int rr = g >> 5;
    int ko = (g & 31) * 8;
    *(int4*)&Bs[rr * LDB2 + ko] = *(const int4*)&Bt[rr * 256 + ko];
  }

  f32x4v acc[4][2];
#pragma unroll
  for (int m = 0; m < 4; m++)
#pragma unroll
    for (int n = 0; n < 2; n++)
#pragma unroll
      for (int qq = 0; qq < 4; qq++) acc[m][n][qq] = 0.f;

  for (int k0 = 0; k0 < 256; k0 += 64) {
#pragma unroll
    for (int it = 0; it < 8; it++) {
      int g = tid + it * 256;
      int rr = g >> 3;
      int ko = (g & 7) * 8;
      int gr = row0 + rr;
      int4 av = make_int4(0, 0, 0, 0);
      if (gr < M) av = *(const int4*)&A[(size_t)gr * 256 + k0 + ko];
      *(int4*)&As[rr * LDT + ko] = av;
    }
    __syncthreads();
#pragma unroll
    for (int kk = 0; kk < 64; kk += 32) {
      bf16x8 af[4], bfr[2];
#pragma unroll
      for (int m = 0; m < 4; m++)
        af[m] = *(const bf16x8*)&As[(wid * 64 + m * 16 + r16) * LDT + kk + kb];
#pragma unroll
      for (int n = 0; n < 2; n++)
        bfr[n] = *(const bf16x8*)&Bs[(n * 16 + r16) * LDB2 + k0 + kk + kb];
#pragma unroll
      for (int m = 0; m < 4; m++)
#pragma unroll
        for (int n = 0; n < 2; n++)
          acc[m][n] = __builtin_amdgcn_mfma_f32_16x16x32_bf16(af[m], bfr[n], acc[m][n], 0, 0, 0);
    }
    __syncthreads();
  }
#pragma unroll
  for (int m = 0; m < 4; m++) {
#pragma unroll
    for (int n = 0; n < 2; n++) {
#pragma unroll
      for (int qq = 0; qq < 4; qq++) {
        int gr = row0 + wid * 64 + m * 16 + rq + qq;
        if (gr < M) C[(size_t)gr * 32 + n * 16 + r16] = f2bf(acc[m][n][qq]);
      }
    }
  }
}

// ---------------- fused GATv2 layer 1 (1 wave/node, depth-3 prefetch, scalar bases) ----------------
__global__ __launch_bounds__(256) void gat1_kernel(const unsigned short* __restrict__ xlr,
    const float* __restrict__ att, const float* __restrict__ bias,
    const int* __restrict__ offs, const int* __restrict__ csr,
    unsigned short* __restrict__ h, int N) {
  int w = threadIdx.x >> 6, lane = threadIdx.x & 63;
  int i = blockIdx.x * 4 + w;
  if (i >= N) return;
  i = __builtin_amdgcn_readfirstlane(i);
  const uint2* rows = (const uint2*)xlr;
  const uint2* rowi = rows + (size_t)i * 128;
  uint2 ul = rowi[lane];
  uint2 ur = rowi[64 + lane];
  f32x2 xl01 = bfpair(ul.x), xl23 = bfpair(ul.y);
  f32x2 xr01 = bfpair(ur.x), xr23 = bfpair(ur.y);
  float4 a4 = ((const float4*)att)[lane];
  f32x2 a01; a01.x = a4.x; a01.y = a4.y;
  f32x2 a23; a23.x = a4.z; a23.y = a4.w;

  f32x2 t01 = xl01 + xr01, t23 = xl23 + xr23;
  f32x2 l01 = __builtin_elementwise_max(t01, t01 * NEG);
  f32x2 l23 = __builtin_elementwise_max(t23, t23 * NEG);
  f32x2 ps = l01 * a01 + l23 * a23;
  float p = ps.x + ps.y;
  p += __shfl_xor(p, 1, 8);
  p += __shfl_xor(p, 2, 8);
  p += __shfl_xor(p, 4, 8);
  float m = p, ssum = 1.f;
  f32x2 O01 = xl01, O23 = xl23;

  int e = offs[i], end = offs[i + 1];
  int rem = end - e;

  int ja0 = __builtin_amdgcn_readfirstlane(rem > 0 ? csr[e + 0] : i);
  int ja1 = __builtin_amdgcn_readfirstlane(rem > 1 ? csr[e + 1] : i);
  uint2 ua0 = rows[(size_t)ja0 * 128 + lane];
  uint2 ua1 = rows[(size_t)ja1 * 128 + lane];
  int jb0 = __builtin_amdgcn_readfirstlane(rem > 2 ? csr[e + 2] : i);
  int jb1 = __builtin_amdgcn_readfirstlane(rem > 3 ? csr[e + 3] : i);
  uint2 ub0 = rows[(size_t)jb0 * 128 + lane];
  uint2 ub1 = rows[(size_t)jb1 * 128 + lane];
  int jc0 = __builtin_amdgcn_readfirstlane(rem > 4 ? csr[e + 4] : i);
  int jc1 = __builtin_amdgcn_readfirstlane(rem > 5 ? csr[e + 5] : i);
  uint2 uc0 = rows[(size_t)jc0 * 128 + lane];
  uint2 uc1 = rows[(size_t)jc1 * 128 + lane];

  while (rem >= 2) {
    int jn0 = __builtin_amdgcn_readfirstlane(rem > 6 ? csr[e + 6] : i);
    int jn1 = __builtin_amdgcn_readfirstlane(rem > 7 ? csr[e + 7] : i);
    uint2 un0 = rows[(size_t)jn0 * 128 + lane];
    uint2 un1 = rows[(size_t)jn1 * 128 + lane];
    f32x2 x001 = bfpair(ua0.x), x023 = bfpair(ua0.y);
    f32x2 x101 = bfpair(ua1.x), x123 = bfpair(ua1.y);
    f32x2 q01 = x001 + xr01, q23 = x023 + xr23;
    f32x2 r01 = x101 + xr01, r23 = x123 + xr23;
    f32x2 g01 = __builtin_elementwise_max(q01, q01 * NEG);
    f32x2 g23 = __builtin_elementwise_max(q23, q23 * NEG);
    f32x2 k01 = __builtin_elementwise_max(r01, r01 * NEG);
    f32x2 k23 = __builtin_elementwise_max(r23, r23 * NEG);
    f32x2 s0v = g01 * a01 + g23 * a23;
    f32x2 s1v = k01 * a01 + k23 * a23;
    float p0 = s0v.x + s0v.y;
    float p1 = s1v.x + s1v.y;
    p0 += __shfl_xor(p0, 1, 8);
    p1 += __shfl_xor(p1, 1, 8);
    p0 += __shfl_xor(p0, 2, 8);
    p1 += __shfl_xor(p1, 2, 8);
    p0 += __shfl_xor(p0, 4, 8);
    p1 += __shfl_xor(p1, 4, 8);
    float mx = fmaxf(p0, p1);
    if (!__all(mx <= m + 8.f)) {        // defer-max (T13)
      float mn = fmaxf(m, mx);
      float sc = __expf(m - mn);
      O01 *= sc; O23 *= sc; ssum *= sc; m = mn;
    }
    float w0 = __expf(p0 - m), w1 = __expf(p1 - m);
    O01 += w0 * x001 + w1 * x101;
    O23 += w0 * x023 + w1 * x123;
    ssum += w0 + w1;
    ua0 = ub0; ua1 = ub1;
    ub0 = uc0; ub1 = uc1;
    uc0 = un0; uc1 = un1;
    e += 2; rem -= 2;
  }
  if (rem == 1) {
    f32x2 x001 = bfpair(ua0.x), x023 = bfpair(ua0.y);
    f32x2 q01 = x001 + xr01, q23 = x023 + xr23;
    f32x2 g01 = __builtin_elementwise_max(q01, q01 * NEG);
    f32x2 g23 = __builtin_elementwise_max(q23, q23 * NEG);
    f32x2 s0v = g01 * a01 + g23 * a23;
    float p0 = s0v.x + s0v.y;
    p0 += __shfl_xor(p0, 1, 8);
    p0 += __shfl_xor(p0, 2, 8);
    p0 += __shfl_xor(p0, 4, 8);
    if (!__all(p0 <= m + 8.f)) {
      float mn = fmaxf(m, p0);
      float sc = __expf(m - mn);
      O01 *= sc; O23 *= sc; ssum *= sc; m = mn;
    }
    float w0 = __expf(p0 - m);
    O01 += w0 * x001;
    O23 += w0 * x023;
    ssum += w0;
  }
  float inv = 1.f / (ssum + 1e-16f);
  float4 b4 = ((const float4*)bias)[lane];
  float h0 = O01.x * inv + b4.x;
  float h1 = O01.y * inv + b4.y;
  float h2 = O23.x * inv + b4.z;
  float h3 = O23.y * inv + b4.w;
  h0 = h0 > 0.f ? h0 : (__expf(h0) - 1.f);
  h1 = h1 > 0.f ? h1 : (__expf(h1) - 1.f);
  h2 = h2 > 0.f ? h2 : (__expf(h2) - 1.f);
  h3 = h3 > 0.f ? h3 : (__expf(h3) - 1.f);
  ushort4 o;
  o.x = f2bf(h0); o.y = f2bf(h1); o.z = f2bf(h2); o.w = f2bf(h3);
  ((ushort4*)(h + (size_t)i * 256))[lane] = o;
}

// ---------------- fused GATv2 layer 2 (bf16 in, depth-3 prefetch, defer-max) ----------------
__global__ __launch_bounds__(256) void gat2_kernel(const unsigned short* __restrict__ xlr2,
    const float* __restrict__ att, const float* __restrict__ b2,
    const int* __restrict__ offs, const int* __restrict__ csr,
    float* __restrict__ yout, int N) {
  int grp = threadIdx.x >> 4, c = threadIdx.x & 15;
  int i = blockIdx.x * 16 + grp;
  if (i >= N) return;
  float xli = bf2f(xlr2[(size_t)i * 32 + c]);
  float xri = bf2f(xlr2[(size_t)i * 32 + 16 + c]);
  float a = att[c];
  float v = xli + xri; v = fmaxf(v, NEG * v);
  float p = v * a;
#pragma unroll
  for (int o = 8; o >= 1; o >>= 1) p += __shfl_xor(p, o, 16);
  float m = p, ssum = 1.0f, O = xli;

  int e = offs[i], end = offs[i + 1];
  int rem = end - e;

  int ja0 = rem > 0 ? csr[e + 0] : i;
  int ja1 = rem > 1 ? csr[e + 1] : i;
  float xa0 = bf2f(xlr2[(size_t)ja0 * 32 + c]);
  float xa1 = bf2f(xlr2[(size_t)ja1 * 32 + c]);
  int jb0 = rem > 2 ? csr[e + 2] : i;
  int jb1 = rem > 3 ? csr[e + 3] : i;
  float xb0 = bf2f(xlr2[(size_t)jb0 * 32 + c]);
  float xb1 = bf2f(xlr2[(size_t)jb1 * 32 + c]);
  int jc0 = rem > 4 ? csr[e + 4] : i;
  int jc1 = rem > 5 ? csr[e + 5] : i;
  float xc0 = bf2f(xlr2[(size_t)jc0 * 32 + c]);
  float xc1 = bf2f(xlr2[(size_t)jc1 * 32 + c]);

  while (rem >= 2) {
    int jn0 = rem > 6 ? csr[e + 6] : i;
    int jn1 = rem > 7 ? csr[e + 7] : i;
    float xn0 = bf2f(xlr2[(size_t)jn0 * 32 + c]);
    float xn1 = bf2f(xlr2[(size_t)jn1 * 32 + c]);
    float q0 = xa0 + xri; q0 = fmaxf(q0, NEG * q0);
    float q1 = xa1 + xri; q1 = fmaxf(q1, NEG * q1);
    float p0 = q0 * a, p1 = q1 * a;
#pragma unroll
    for (int o = 8; o >= 1; o >>= 1) {
      p0 += __shfl_xor(p0, o, 16);
      p1 += __shfl_xor(p1, o, 16);
    }
    float mx = fmaxf(p0, p1);
    if (!__all(mx <= m + 8.f)) {
      float mn = fmaxf(m, mx);
      float sc = __expf(m - mn);
      O *= sc; ssum *= sc; m = mn;
    }
    float w0 = __expf(p0 - m), w1 = __expf(p1 - m);
    O += w0 * xa0 + w1 * xa1;
    ssum += w0 + w1;
    xa0 = xb0; xa1 = xb1;
    xb0 = xc0; xb1 = xc1;
    xc0 = xn0; xc1 = xn1;
    e += 2; rem -= 2;
  }
  if (rem == 1) {
    float q0 = xa0 + xri; q0 = fmaxf(q0, NEG * q0);
    float p0 = q0 * a;
#pragma unroll
    for (int o = 8; o >= 1; o >>= 1) p0 += __shfl_xor(p0, o, 16);
    if (!__all(p0 <= m + 8.f)) {
      float mn = fmaxf(m, p0);
      float sc = __expf(m - mn);
      O *= sc; ssum *= sc; m = mn;
    }
    float w0 = __expf(p0 - m);
    O += w0 * xa0;
    ssum += w0;
  }
  yout[(size_t)i * C2 + c] = O / (ssum + 1e-16f) + b2[c];
}

// ---------------- finalize ----------------
__global__ __launch_bounds__(256) void finalize_kernel(const float* __restrict__ y,
    const float* __restrict__ z, float* __restrict__ out, int N) {
  int grp = threadIdx.x >> 4, c = threadIdx.x & 15;
  int i = blockIdx.x * 16 + grp;
  if (i >= N) return;
  float yv = y[(size_t)i * C2 + c];
  float zv = z[(size_t)i * C2 + c];
  float my = yv;
#pragma unroll
  for (int o = 8; o >= 1; o >>= 1) my = fmaxf(my, __shfl_xor(my, o, 16));
  float sy = __expf(yv - my);
#pragma unroll
  for (int o = 8; o >= 1; o >>= 1) sy += __shfl_xor(sy, o, 16);
  float lpy = yv - my - __logf(sy);
  float mz = zv;
#pragma unroll
  for (int o = 8; o >= 1; o >>= 1) mz = fmaxf(mz, __shfl_xor(mz, o, 16));
  float sz = __expf(zv - mz);
#pragma unroll
  for (int o = 8; o >= 1; o >>= 1) sz += __shfl_xor(sz, o, 16);
  float lpz = zv - mz - __logf(sz);
  float dot = yv * zv, ny2 = yv * yv, nz2 = zv * zv;
#pragma unroll
  for (int o = 8; o >= 1; o >>= 1) {
    dot += __shfl_xor(dot, o, 16);
    ny2 += __shfl_xor(ny2, o, 16);
    nz2 += __shfl_xor(nz2, o, 16);
  }
  float ny = fmaxf(sqrtf(ny2), 1e-8f);
  float nz = fmaxf(sqrtf(nz2), 1e-8f);
  float cosv = dot / (ny * nz);
  size_t o1 = (size_t)N * C2;
  size_t o2 = o1 + N;
  size_t o3 = o2 + (size_t)N * C2;
  size_t o4 = o3 + (size_t)N * C2;
  size_t idx = (size_t)i * C2 + c;
  out[idx] = lpy;
  if (c == 0) out[o1 + i] = 1.0f - cosv;
  out[o2 + idx] = lpz;
  out[o3 + idx] = lpy;
  out[o4 + idx] = lpy;
}

extern "C" void kernel_launch(void* const* d_in, const int* in_sizes, int n_in,
                              void* d_out, int out_size, void* d_ws, size_t ws_size,
                              hipStream_t stream) {
  const float* x1   = (const float*)d_in[0];
  const int*   ei1  = (const int*)d_in[1];
  const float* x2   = (const float*)d_in[2];
  const int*   ei2  = (const int*)d_in[3];
  const float* W1l  = (const float*)d_in[4];
  const float* W1r  = (const float*)d_in[5];
  const float* att1 = (const float*)d_in[6];
  const float* b1   = (const float*)d_in[7];
  const float* W2l  = (const float*)d_in[8];
  const float* W2r  = (const float*)d_in[9];
  const float* att2 = (const float*)d_in[10];
  const float* b2   = (const float*)d_in[11];
  const int N = in_sizes[0] / FIN;
  const int E = in_sizes[1] / 2;
  float* out = (float*)d_out;

  char* w = (char*)d_ws;
  size_t off = 0;
  auto carve = [&](size_t bytes) -> void* {
    void* p = w + off;
    off += (bytes + 255) & ~(size_t)255;
    return p;
  };
  unsigned short* xlr_b = (unsigned short*)carve((size_t)N * 512 * 2);
  unsigned short* h     = (unsigned short*)carve((size_t)N * 256 * 2);
  unsigned short* Wt    = (unsigned short*)carve(512 * 256 * 2);
  unsigned short* Wt2   = (unsigned short*)carve(32 * 256 * 2);
  unsigned short* xlr2b = (unsigned short*)carve((size_t)N * 32 * 2);
  float* yb   = (float*)carve((size_t)N * 16 * 4);
  float* zb   = (float*)carve((size_t)N * 16 * 4);
  int* deg2 = (int*)carve((size_t)2 * N * 4);
  int* cnt2 = (int*)carve((size_t)2 * N * 4);
  int* offs = (int*)carve((size_t)(N + 1) * 4);
  int* csr  = (int*)carve((size_t)E * 4);
  int* partials = (int*)carve(64 * 4);
  (void)ws_size; (void)n_in; (void)out_size;

  const size_t zero_bytes = (size_t)((char*)cnt2 - (char*)deg2) + (size_t)2 * N * 4;
  hipMemsetAsync(deg2, 0, zero_bytes, stream);

  const int NB = (N + 1023) / 1024;

  cvt_w_kernel<<<512, 256, 0, stream>>>(W1l, W1r, Wt);
  cvt_w2_kernel<<<32, 256, 0, stream>>>(W2l, W2r, Wt2);

  for (int g = 0; g < 2; g++) {
    const float* x  = g ? x2 : x1;
    const int*   ei = g ? ei2 : ei1;
    float* yout = g ? zb : yb;
    int* deg = deg2 + (size_t)g * N;
    int* cnt = cnt2 + (size_t)g * N;
    const int* srcp = ei;
    const int* dstp = ei + E;

    deg_kernel<<<(E + 255) / 256, 256, 0, stream>>>(dstp, deg, E);
    scan_part_kernel<<<NB, 1024, 0, stream>>>(deg, offs, partials, N);
    scan_fix_kernel<<<NB, 1024, 0, stream>>>(offs, partials, NB, N);
    fill_kernel<<<(E + 255) / 256, 256, 0, stream>>>(srcp, dstp, offs, cnt, csr, E);

    int RB = (N + 127) / 128;
    gemm_mfma_kernel<<<RB * 4, 256, 0, stream>>>(x, Wt, xlr_b, N);
    gat1_kernel<<<(N + 3) / 4, 256, 0, stream>>>(xlr_b, att1, b1, offs, csr, h, N);
    gemm2_mfma_kernel<<<(N + 255) / 256, 256, 0, stream>>>(h, Wt2, xlr2b, N);
    gat2_kernel<<<(N + 15) / 16, 256, 0, stream>>>(xlr2b, att2, b2, offs, csr, yout, N);
  }
  finalize_kernel<<<(N + 15) / 16, 256, 0, stream>>>(yb, zb, out, N);
}

// Round 9
// 470.031 us; speedup vs baseline: 1.0720x; 1.0720x over previous
//
#include <hip/hip_runtime.h>
#include <hip/hip_bf16.h>
#include <math.h>

#define FIN 256
#define F1  256   // H1*HID = 8*32
#define C2  16
#define NEG 0.2f

typedef short bf16x8 __attribute__((ext_vector_type(8)));
typedef float f32x4v __attribute__((ext_vector_type(4)));
typedef float f32x2 __attribute__((ext_vector_type(2)));

__device__ __forceinline__ float bf2f(unsigned short u) {
  union { float f; unsigned int i; } c; c.i = ((unsigned int)u) << 16; return c.f;
}
__device__ __forceinline__ unsigned short f2bf(float f) {
  __hip_bfloat16 b = __float2bfloat16(f);
  return *(unsigned short*)&b;
}
// two bf16 packed in a u32 -> two f32
__device__ __forceinline__ f32x2 bfpair(unsigned int u) {
  union { float f; unsigned int i; } lo, hi;
  lo.i = u << 16;
  hi.i = u & 0xffff0000u;
  f32x2 r; r.x = lo.f; r.y = hi.f; return r;
}

// ---------------- CSR build ----------------
__global__ __launch_bounds__(256) void deg_kernel(const int* __restrict__ dst,
                                                  int* __restrict__ deg, int E) {
  int e = blockIdx.x * blockDim.x + threadIdx.x;
  if (e < E) atomicAdd(&deg[dst[e]], 1);
}

__global__ __launch_bounds__(1024) void scan_part_kernel(const int* __restrict__ deg,
    int* __restrict__ offs, int* __restrict__ partials, int n) {
  __shared__ int wsum[16], wpref[16];
  int tid = threadIdx.x, lane = tid & 63, wid = tid >> 6;
  int idx = blockIdx.x * 1024 + tid;
  int v = (idx < n) ? deg[idx] : 0;
  int s = v;
#pragma unroll
  for (int o = 1; o < 64; o <<= 1) {
    int t = __shfl_up(s, o, 64);
    if (lane >= o) s += t;
  }
  if (lane == 63) wsum[wid] = s;
  __syncthreads();
  if (tid < 16) {
    int t = wsum[tid];
    int ss = t;
#pragma unroll
    for (int o = 1; o < 16; o <<= 1) {
      int u = __shfl_up(ss, o, 16);
      if (tid >= o) ss += u;
    }
    wpref[tid] = ss - t;
    if (tid == 15) partials[blockIdx.x] = ss;
  }
  __syncthreads();
  if (idx < n) offs[idx] = wpref[wid] + s - v;
}

// fused: re-scan partials in every block; block 0 writes total, blocks b>0 add carry
__global__ __launch_bounds__(1024) void scan_fix_kernel(int* __restrict__ offs,
    const int* __restrict__ partials, int nb, int n) {
  __shared__ int carry_s;
  int tid = threadIdx.x;
  int b = blockIdx.x;
  if (tid < 64) {
    int v = (tid < nb) ? partials[tid] : 0;
    int s = v;
#pragma unroll
    for (int o = 1; o < 64; o <<= 1) {
      int t = __shfl_up(s, o, 64);
      if (tid >= o) s += t;
    }
    if (b == 0) {
      if (tid == nb - 1) offs[n] = s;
    } else if (tid == b - 1) {
      carry_s = s;
    }
  }
  __syncthreads();
  if (b > 0) {
    int idx = b * 1024 + tid;
    if (idx < n) offs[idx] += carry_s;
  }
}

__global__ __launch_bounds__(256) void fill_kernel(const int* __restrict__ src,
    const int* __restrict__ dst, const int* __restrict__ offs,
    int* __restrict__ cnt, int* __restrict__ csr, int E) {
  int e = blockIdx.x * blockDim.x + threadIdx.x;
  if (e < E) {
    int d = dst[e];
    int pos = offs[d] + atomicAdd(&cnt[d], 1);
    csr[pos] = src[e];
  }
}

// ---------------- weight converts (tiny, once) ----------------
__global__ __launch_bounds__(256) void cvt_w_kernel(const float* __restrict__ Wl,
    const float* __restrict__ Wr, unsigned short* __restrict__ Wt) {
  int n = blockIdx.x;
  int k = threadIdx.x;
  float v = (n < 256) ? Wl[k * 256 + n] : Wr[k * 256 + (n - 256)];
  Wt[n * 256 + k] = f2bf(v);
}

__global__ __launch_bounds__(256) void cvt_w2_kernel(const float* __restrict__ Wl,
    const float* __restrict__ Wr, unsigned short* __restrict__ Wt2) {
  int c = blockIdx.x;
  int k = threadIdx.x;
  float v = (c < 16) ? Wl[k * 16 + c] : Wr[k * 16 + (c - 16)];
  Wt2[c * 256 + k] = f2bf(v);
}

// ---------------- MFMA GEMM: 128x128 tile, 8 waves (64x32 each), BK=64, A+B in LDS ----------------
// Low per-wave register footprint (acc 4x2 = 32 AGPR) -> ~3 blocks/CU co-resident.
#define LDT 72
__global__ __launch_bounds__(512) void gemm_mfma_kernel(
    const float* __restrict__ A, const unsigned short* __restrict__ Bt,
    unsigned short* __restrict__ C, int M) {
  __shared__ __align__(16) unsigned short As[128 * LDT];
  __shared__ __align__(16) unsigned short Bs[128 * LDT];
  int tid = threadIdx.x;
  // bijective XCD swizzle (m204)
  int G = gridDim.x;
  int q = G >> 3, r = G & 7;
  int b = blockIdx.x;
  int xcd = b & 7, pos = b >> 3;
  int swz = (xcd < r) ? xcd * (q + 1) + pos : r * (q + 1) + (xcd - r) * q + pos;
  int row0 = (swz >> 2) * 128;
  int col0 = (swz & 3) * 128;
  int wid = tid >> 6, lane = tid & 63;
  int wr = wid >> 2, wc = wid & 3;          // 2 x 4 wave grid; wave = 64 rows x 32 cols
  int r16 = lane & 15, kb = (lane >> 4) * 8;

  f32x4v acc[4][2];
#pragma unroll
  for (int m = 0; m < 4; m++)
#pragma unroll
    for (int n = 0; n < 2; n++)
#pragma unroll
      for (int qq = 0; qq < 4; qq++) acc[m][n][qq] = 0.f;

  for (int k0 = 0; k0 < 256; k0 += 64) {
#pragma unroll
    for (int it = 0; it < 2; it++) {
      int g = tid + it * 512;         // 0..1023 granules of 8 elems
      int rr = g >> 3;
      int ko = (g & 7) * 8;
      int gr = row0 + rr;
      float4 a0 = make_float4(0.f, 0.f, 0.f, 0.f);
      float4 a1 = make_float4(0.f, 0.f, 0.f, 0.f);
      if (gr < M) {
        a0 = *(const float4*)&A[(size_t)gr * 256 + k0 + ko];
        a1 = *(const float4*)&A[(size_t)gr * 256 + k0 + ko + 4];
      }
      ushort4 lo, hi;
      lo.x = f2bf(a0.x); lo.y = f2bf(a0.y); lo.z = f2bf(a0.z); lo.w = f2bf(a0.w);
      hi.x = f2bf(a1.x); hi.y = f2bf(a1.y); hi.z = f2bf(a1.z); hi.w = f2bf(a1.w);
      *(ushort4*)&As[rr * LDT + ko] = lo;
      *(ushort4*)&As[rr * LDT + ko + 4] = hi;
      int4 bv = *(const int4*)&Bt[(size_t)(col0 + rr) * 256 + k0 + ko];
      *(int4*)&Bs[rr * LDT + ko] = bv;
    }
    __syncthreads();
#pragma unroll
    for (int kk = 0; kk < 64; kk += 32) {
      bf16x8 af[4], bfr[2];
#pragma unroll
      for (int m = 0; m < 4; m++)
        af[m] = *(const bf16x8*)&As[(wr * 64 + m * 16 + r16) * LDT + kk + kb];
#pragma unroll
      for (int n = 0; n < 2; n++)
        bfr[n] = *(const bf16x8*)&Bs[(wc * 32 + n * 16 + r16) * LDT + kk + kb];
#pragma unroll
      for (int m = 0; m < 4; m++)
#pragma unroll
        for (int n = 0; n < 2; n++)
          acc[m][n] = __builtin_amdgcn_mfma_f32_16x16x32_bf16(af[m], bfr[n], acc[m][n], 0, 0, 0);
    }
    __syncthreads();
  }
  int rq = (lane >> 4) * 4;
#pragma unroll
  for (int m = 0; m < 4; m++) {
#pragma unroll
    for (int n = 0; n < 2; n++) {
#pragma unroll
      for (int qq = 0; qq < 4; qq++) {
        int gr = row0 + wr * 64 + m * 16 + rq + qq;
        if (gr < M) {
          int gc = col0 + wc * 32 + n * 16 + r16;
          C[(size_t)gr * 512 + gc] = f2bf(acc[m][n][qq]);
        }
      }
    }
  }
}

// ---------------- layer-2 MFMA GEMM: C[M,32](bf16) = h[M,256](bf16) @ Wt2^T ----------------
#define LDB2 264
__global__ __launch_bounds__(256) void gemm2_mfma_kernel(
    const unsigned short* __restrict__ A, const unsigned short* __restrict__ Bt,
    unsigned short* __restrict__ C, int M) {
  __shared__ __align__(16) unsigned short As[256 * LDT];
  __shared__ __align__(16) unsigned short Bs[32 * LDB2];
  int tid = threadIdx.x;
  int row0 = blockIdx.x * 256;
  int wid = tid >> 6, lane = tid & 63;
  int r16 = lane & 15, kb = (lane >> 4) * 8, rq = (lane >> 4) * 4;

#pragma unroll
  for (int it = 0; it < 4; it++) {
    int g = tid + it * 256;
    int rr = g >> 5;
    int ko = (g & 31) * 8;
    *(int4*)&Bs[rr * LDB2 + ko] = *(const int4*)&Bt[rr * 256 + ko];
  }

  f32x4v acc[4][2];
#pragma unroll
  for (int m = 0; m < 4; m++)
#pragma unroll
    for (int n = 0; n < 2; n++)
#pragma unroll
      for (int qq = 0; qq < 4; qq++) acc[m][n][qq] = 0.f;

  for (int k0 = 0; k0 < 256; k0 += 64) {
#pragma unroll
    for (int it = 0; it < 8; it++) {
      int g = tid + it * 256;
      int rr = g >> 3;
      int ko = (g & 7) * 8;
      int gr = row0 + rr;
      int4 av = make_int4(0, 0, 0, 0);
      if (gr < M) av = *(const int4*)&A[(size_t)gr * 256 + k0 + ko];
      *(int4*)&As[rr * LDT + ko] = av;
    }
    __syncthreads();
#pragma unroll
    for (int kk = 0; kk < 64; kk += 32) {
      bf16x8 af[4], bfr[2];
#pragma unroll
      for (int m = 0; m < 4; m++)
        af[m] = *(const bf16x8*)&As[(wid * 64 + m * 16 + r16) * LDT + kk + kb];
#pragma unroll
      for (int n = 0; n < 2; n++)
        bfr[n] = *(const bf16x8*)&Bs[(n * 16 + r16) * LDB2 + k0 + kk + kb];
#pragma unroll
      for (int m = 0; m < 4; m++)
#pragma unroll
        for (int n = 0; n < 2; n++)
          acc[m][n] = __builtin_amdgcn_mfma_f32_16x16x32_bf16(af[m], bfr[n], acc[m][n], 0, 0, 0);
    }
    __syncthreads();
  }
#pragma unroll
  for (int m = 0; m < 4; m++) {
#pragma unroll
    for (int n = 0; n < 2; n++) {
#pragma unroll
      for (int qq = 0; qq < 4; qq++) {
        int gr = row0 + wid * 64 + m * 16 + rq + qq;
        if (gr < M) C[(size_t)gr * 32 + n * 16 + r16] = f2bf(acc[m][n][qq]);
      }
    }
  }
}

// ---------------- fused GATv2 layer 1 (1 wave/node, depth-3 prefetch, scalar bases) ----------------
__global__ __launch_bounds__(256) void gat1_kernel(const unsigned short* __restrict__ xlr,
    const float* __restrict__ att, const float* __restrict__ bias,
    const int* __restrict__ offs, const int* __restrict__ csr,
    unsigned short* __restrict__ h, int N) {
  int w = threadIdx.x >> 6, lane = threadIdx.x & 63;
  int i = blockIdx.x * 4 + w;
  if (i >= N) return;
  i = __builtin_amdgcn_readfirstlane(i);
  const uint2* rows = (const uint2*)xlr;
  const uint2* rowi = rows + (size_t)i * 128;
  uint2 ul = rowi[lane];
  uint2 ur = rowi[64 + lane];
  f32x2 xl01 = bfpair(ul.x), xl23 = bfpair(ul.y);
  f32x2 xr01 = bfpair(ur.x), xr23 = bfpair(ur.y);
  float4 a4 = ((const float4*)att)[lane];
  f32x2 a01; a01.x = a4.x; a01.y = a4.y;
  f32x2 a23; a23.x = a4.z; a23.y = a4.w;

  f32x2 t01 = xl01 + xr01, t23 = xl23 + xr23;
  f32x2 l01 = __builtin_elementwise_max(t01, t01 * NEG);
  f32x2 l23 = __builtin_elementwise_max(t23, t23 * NEG);
  f32x2 ps = l01 * a01 + l23 * a23;
  float p = ps.x + ps.y;
  p += __shfl_xor(p, 1, 8);
  p += __shfl_xor(p, 2, 8);
  p += __shfl_xor(p, 4, 8);
  float m = p, ssum = 1.f;
  f32x2 O01 = xl01, O23 = xl23;

  int e = offs[i], end = offs[i + 1];
  int rem = end - e;

  int ja0 = __builtin_amdgcn_readfirstlane(rem > 0 ? csr[e + 0] : i);
  int ja1 = __builtin_amdgcn_readfirstlane(rem > 1 ? csr[e + 1] : i);
  uint2 ua0 = rows[(size_t)ja0 * 128 + lane];
  uint2 ua1 = rows[(size_t)ja1 * 128 + lane];
  int jb0 = __builtin_amdgcn_readfirstlane(rem > 2 ? csr[e + 2] : i);
  int jb1 = __builtin_amdgcn_readfirstlane(rem > 3 ? csr[e + 3] : i);
  uint2 ub0 = rows[(size_t)jb0 * 128 + lane];
  uint2 ub1 = rows[(size_t)jb1 * 128 + lane];
  int jc0 = __builtin_amdgcn_readfirstlane(rem > 4 ? csr[e + 4] : i);
  int jc1 = __builtin_amdgcn_readfirstlane(rem > 5 ? csr[e + 5] : i);
  uint2 uc0 = rows[(size_t)jc0 * 128 + lane];
  uint2 uc1 = rows[(size_t)jc1 * 128 + lane];

  while (rem >= 2) {
    int jn0 = __builtin_amdgcn_readfirstlane(rem > 6 ? csr[e + 6] : i);
    int jn1 = __builtin_amdgcn_readfirstlane(rem > 7 ? csr[e + 7] : i);
    uint2 un0 = rows[(size_t)jn0 * 128 + lane];
    uint2 un1 = rows[(size_t)jn1 * 128 + lane];
    f32x2 x001 = bfpair(ua0.x), x023 = bfpair(ua0.y);
    f32x2 x101 = bfpair(ua1.x), x123 = bfpair(ua1.y);
    f32x2 q01 = x001 + xr01, q23 = x023 + xr23;
    f32x2 r01 = x101 + xr01, r23 = x123 + xr23;
    f32x2 g01 = __builtin_elementwise_max(q01, q01 * NEG);
    f32x2 g23 = __builtin_elementwise_max(q23, q23 * NEG);
    f32x2 k01 = __builtin_elementwise_max(r01, r01 * NEG);
    f32x2 k23 = __builtin_elementwise_max(r23, r23 * NEG);
    f32x2 s0v = g01 * a01 + g23 * a23;
    f32x2 s1v = k01 * a01 + k23 * a23;
    float p0 = s0v.x + s0v.y;
    float p1 = s1v.x + s1v.y;
    p0 += __shfl_xor(p0, 1, 8);
    p1 += __shfl_xor(p1, 1, 8);
    p0 += __shfl_xor(p0, 2, 8);
    p1 += __shfl_xor(p1, 2, 8);
    p0 += __shfl_xor(p0, 4, 8);
    p1 += __shfl_xor(p1, 4, 8);
    float mx = fmaxf(p0, p1);
    if (!__all(mx <= m + 8.f)) {        // defer-max (T13)
      float mn = fmaxf(m, mx);
      float sc = __expf(m - mn);
      O01 *= sc; O23 *= sc; ssum *= sc; m = mn;
    }
    float w0 = __expf(p0 - m), w1 = __expf(p1 - m);
    O01 += w0 * x001 + w1 * x101;
    O23 += w0 * x023 + w1 * x123;
    ssum += w0 + w1;
    ua0 = ub0; ua1 = ub1;
    ub0 = uc0; ub1 = uc1;
    uc0 = un0; uc1 = un1;
    e += 2; rem -= 2;
  }
  if (rem == 1) {
    f32x2 x001 = bfpair(ua0.x), x023 = bfpair(ua0.y);
    f32x2 q01 = x001 + xr01, q23 = x023 + xr23;
    f32x2 g01 = __builtin_elementwise_max(q01, q01 * NEG);
    f32x2 g23 = __builtin_elementwise_max(q23, q23 * NEG);
    f32x2 s0v = g01 * a01 + g23 * a23;
    float p0 = s0v.x + s0v.y;
    p0 += __shfl_xor(p0, 1, 8);
    p0 += __shfl_xor(p0, 2, 8);
    p0 += __shfl_xor(p0, 4, 8);
    if (!__all(p0 <= m + 8.f)) {
      float mn = fmaxf(m, p0);
      float sc = __expf(m - mn);
      O01 *= sc; O23 *= sc; ssum *= sc; m = mn;
    }
    float w0 = __expf(p0 - m);
    O01 += w0 * x001;
    O23 += w0 * x023;
    ssum += w0;
  }
  float inv = 1.f / (ssum + 1e-16f);
  float4 b4 = ((const float4*)bias)[lane];
  float h0 = O01.x * inv + b4.x;
  float h1 = O01.y * inv + b4.y;
  float h2 = O23.x * inv + b4.z;
  float h3 = O23.y * inv + b4.w;
  h0 = h0 > 0.f ? h0 : (__expf(h0) - 1.f);
  h1 = h1 > 0.f ? h1 : (__expf(h1) - 1.f);
  h2 = h2 > 0.f ? h2 : (__expf(h2) - 1.f);
  h3 = h3 > 0.f ? h3 : (__expf(h3) - 1.f);
  ushort4 o;
  o.x = f2bf(h0); o.y = f2bf(h1); o.z = f2bf(h2); o.w = f2bf(h3);
  ((ushort4*)(h + (size_t)i * 256))[lane] = o;
}

// ---------------- fused GATv2 layer 2 (bf16 in, depth-3 prefetch, defer-max) ----------------
__global__ __launch_bounds__(256) void gat2_kernel(const unsigned short* __restrict__ xlr2,
    const float* __restrict__ att, const float* __restrict__ b2,
    const int* __restrict__ offs, const int* __restrict__ csr,
    float* __restrict__ yout, int N) {
  int grp = threadIdx.x >> 4, c = threadIdx.x & 15;
  int i = blockIdx.x * 16 + grp;
  if (i >= N) return;
  float xli = bf2f(xlr2[(size_t)i * 32 + c]);
  float xri = bf2f(xlr2[(size_t)i * 32 + 16 + c]);
  float a = att[c];
  float v = xli + xri; v = fmaxf(v, NEG * v);
  float p = v * a;
#pragma unroll
  for (int o = 8; o >= 1; o >>= 1) p += __shfl_xor(p, o, 16);
  float m = p, ssum = 1.0f, O = xli;

  int e = offs[i], end = offs[i + 1];
  int rem = end - e;

  int ja0 = rem > 0 ? csr[e + 0] : i;
  int ja1 = rem > 1 ? csr[e + 1] : i;
  float xa0 = bf2f(xlr2[(size_t)ja0 * 32 + c]);
  float xa1 = bf2f(xlr2[(size_t)ja1 * 32 + c]);
  int jb0 = rem > 2 ? csr[e + 2] : i;
  int jb1 = rem > 3 ? csr[e + 3] : i;
  float xb0 = bf2f(xlr2[(size_t)jb0 * 32 + c]);
  float xb1 = bf2f(xlr2[(size_t)jb1 * 32 + c]);
  int jc0 = rem > 4 ? csr[e + 4] : i;
  int jc1 = rem > 5 ? csr[e + 5] : i;
  float xc0 = bf2f(xlr2[(size_t)jc0 * 32 + c]);
  float xc1 = bf2f(xlr2[(size_t)jc1 * 32 + c]);

  while (rem >= 2) {
    int jn0 = rem > 6 ? csr[e + 6] : i;
    int jn1 = rem > 7 ? csr[e + 7] : i;
    float xn0 = bf2f(xlr2[(size_t)jn0 * 32 + c]);
    float xn1 = bf2f(xlr2[(size_t)jn1 * 32 + c]);
    float q0 = xa0 + xri; q0 = fmaxf(q0, NEG * q0);
    float q1 = xa1 + xri; q1 = fmaxf(q1, NEG * q1);
    float p0 = q0 * a, p1 = q1 * a;
#pragma unroll
    for (int o = 8; o >= 1; o >>= 1) {
      p0 += __shfl_xor(p0, o, 16);
      p1 += __shfl_xor(p1, o, 16);
    }
    float mx = fmaxf(p0, p1);
    if (!__all(mx <= m + 8.f)) {
      float mn = fmaxf(m, mx);
      float sc = __expf(m - mn);
      O *= sc; ssum *= sc; m = mn;
    }
    float w0 = __expf(p0 - m), w1 = __expf(p1 - m);
    O += w0 * xa0 + w1 * xa1;
    ssum += w0 + w1;
    xa0 = xb0; xa1 = xb1;
    xb0 = xc0; xb1 = xc1;
    xc0 = xn0; xc1 = xn1;
    e += 2; rem -= 2;
  }
  if (rem == 1) {
    float q0 = xa0 + xri; q0 = fmaxf(q0, NEG * q0);
    float p0 = q0 * a;
#pragma unroll
    for (int o = 8; o >= 1; o >>= 1) p0 += __shfl_xor(p0, o, 16);
    if (!__all(p0 <= m + 8.f)) {
      float mn = fmaxf(m, p0);
      float sc = __expf(m - mn);
      O *= sc; ssum *= sc; m = mn;
    }
    float w0 = __expf(p0 - m);
    O += w0 * xa0;
    ssum += w0;
  }
  yout[(size_t)i * C2 + c] = O / (ssum + 1e-16f) + b2[c];
}

// ---------------- finalize ----------------
__global__ __launch_bounds__(256) void finalize_kernel(const float* __restrict__ y,
    const float* __restrict__ z, float* __restrict__ out, int N) {
  int grp = threadIdx.x >> 4, c = threadIdx.x & 15;
  int i = blockIdx.x * 16 + grp;
  if (i >= N) return;
  float yv = y[(size_t)i * C2 + c];
  float zv = z[(size_t)i * C2 + c];
  float my = yv;
#pragma unroll
  for (int o = 8; o >= 1; o >>= 1) my = fmaxf(my, __shfl_xor(my, o, 16));
  float sy = __expf(yv - my);
#pragma unroll
  for (int o = 8; o >= 1; o >>= 1) sy += __shfl_xor(sy, o, 16);
  float lpy = yv - my - __logf(sy);
  float mz = zv;
#pragma unroll
  for (int o = 8; o >= 1; o >>= 1) mz = fmaxf(mz, __shfl_xor(mz, o, 16));
  float sz = __expf(zv - mz);
#pragma unroll
  for (int o = 8; o >= 1; o >>= 1) sz += __shfl_xor(sz, o, 16);
  float lpz = zv - mz - __logf(sz);
  float dot = yv * zv, ny2 = yv * yv, nz2 = zv * zv;
#pragma unroll
  for (int o = 8; o >= 1; o >>= 1) {
    dot += __shfl_xor(dot, o, 16);
    ny2 += __shfl_xor(ny2, o, 16);
    nz2 += __shfl_xor(nz2, o, 16);
  }
  float ny = fmaxf(sqrtf(ny2), 1e-8f);
  float nz = fmaxf(sqrtf(nz2), 1e-8f);
  float cosv = dot / (ny * nz);
  size_t o1 = (size_t)N * C2;
  size_t o2 = o1 + N;
  size_t o3 = o2 + (size_t)N * C2;
  size_t o4 = o3 + (size_t)N * C2;
  size_t idx = (size_t)i * C2 + c;
  out[idx] = lpy;
  if (c == 0) out[o1 + i] = 1.0f - cosv;
  out[o2 + idx] = lpz;
  out[o3 + idx] = lpy;
  out[o4 + idx] = lpy;
}

extern "C" void kernel_launch(void* const* d_in, const int* in_sizes, int n_in,
                              void* d_out, int out_size, void* d_ws, size_t ws_size,
                              hipStream_t stream) {
  const float* x1   = (const float*)d_in[0];
  const int*   ei1  = (const int*)d_in[1];
  const float* x2   = (const float*)d_in[2];
  const int*   ei2  = (const int*)d_in[3];
  const float* W1l  = (const float*)d_in[4];
  const float* W1r  = (const float*)d_in[5];
  const float* att1 = (const float*)d_in[6];
  const float* b1   = (const float*)d_in[7];
  const float* W2l  = (const float*)d_in[8];
  const float* W2r  = (const float*)d_in[9];
  const float* att2 = (const float*)d_in[10];
  const float* b2   = (const float*)d_in[11];
  const int N = in_sizes[0] / FIN;
  const int E = in_sizes[1] / 2;
  float* out = (float*)d_out;

  char* w = (char*)d_ws;
  size_t off = 0;
  auto carve = [&](size_t bytes) -> void* {
    void* p = w + off;
    off += (bytes + 255) & ~(size_t)255;
    return p;
  };
  unsigned short* xlr_b = (unsigned short*)carve((size_t)N * 512 * 2);
  unsigned short* h     = (unsigned short*)carve((size_t)N * 256 * 2);
  unsigned short* Wt    = (unsigned short*)carve(512 * 256 * 2);
  unsigned short* Wt2   = (unsigned short*)carve(32 * 256 * 2);
  unsigned short* xlr2b = (unsigned short*)carve((size_t)N * 32 * 2);
  float* yb   = (float*)carve((size_t)N * 16 * 4);
  float* zb   = (float*)carve((size_t)N * 16 * 4);
  int* deg2 = (int*)carve((size_t)2 * N * 4);
  int* cnt2 = (int*)carve((size_t)2 * N * 4);
  int* offs = (int*)carve((size_t)(N + 1) * 4);
  int* csr  = (int*)carve((size_t)E * 4);
  int* partials = (int*)carve(64 * 4);
  (void)ws_size; (void)n_in; (void)out_size;

  const size_t zero_bytes = (size_t)((char*)cnt2 - (char*)deg2) + (size_t)2 * N * 4;
  hipMemsetAsync(deg2, 0, zero_bytes, stream);

  const int NB = (N + 1023) / 1024;

  cvt_w_kernel<<<512, 256, 0, stream>>>(W1l, W1r, Wt);
  cvt_w2_kernel<<<32, 256, 0, stream>>>(W2l, W2r, Wt2);

  for (int g = 0; g < 2; g++) {
    const float* x  = g ? x2 : x1;
    const int*   ei = g ? ei2 : ei1;
    float* yout = g ? zb : yb;
    int* deg = deg2 + (size_t)g * N;
    int* cnt = cnt2 + (size_t)g * N;
    const int* srcp = ei;
    const int* dstp = ei + E;

    deg_kernel<<<(E + 255) / 256, 256, 0, stream>>>(dstp, deg, E);
    scan_part_kernel<<<NB, 1024, 0, stream>>>(deg, offs, partials, N);
    scan_fix_kernel<<<NB, 1024, 0, stream>>>(offs, partials, NB, N);
    fill_kernel<<<(E + 255) / 256, 256, 0, stream>>>(srcp, dstp, offs, cnt, csr, E);

    int RB = (N + 127) / 128;
    gemm_mfma_kernel<<<RB * 4, 512, 0, stream>>>(x, Wt, xlr_b, N);
    gat1_kernel<<<(N + 3) / 4, 256, 0, stream>>>(xlr_b, att1, b1, offs, csr, h, N);
    gemm2_mfma_kernel<<<(N + 255) / 256, 256, 0, stream>>>(h, Wt2, xlr2b, N);
    gat2_kernel<<<(N + 15) / 16, 256, 0, stream>>>(xlr2b, att2, b2, offs, csr, yout, N);
  }
  finalize_kernel<<<(N + 15) / 16, 256, 0, stream>>>(yb, zb, out, N);
}

// Round 10
// 408.779 us; speedup vs baseline: 1.2326x; 1.1498x over previous
//
#include <hip/hip_runtime.h>
#include <hip/hip_bf16.h>
#include <math.h>

#define FIN 256
#define C2  16
#define NEG 0.2f

typedef short bf16x8 __attribute__((ext_vector_type(8)));
typedef float f32x4v __attribute__((ext_vector_type(4)));
typedef float f32x2 __attribute__((ext_vector_type(2)));

__device__ __forceinline__ float bf2f(unsigned short u) {
  union { float f; unsigned int i; } c; c.i = ((unsigned int)u) << 16; return c.f;
}
__device__ __forceinline__ unsigned short f2bf(float f) {
  __hip_bfloat16 b = __float2bfloat16(f);
  return *(unsigned short*)&b;
}
__device__ __forceinline__ f32x2 bfpair(unsigned int u) {
  union { float f; unsigned int i; } lo, hi;
  lo.i = u << 16;
  hi.i = u & 0xffff0000u;
  f32x2 r; r.x = lo.f; r.y = hi.f; return r;
}

// ---------------- CSR build (both graphs in one pass; node ids are global g*N+j) ----------------
__global__ __launch_bounds__(256) void deg_kernel(const int* __restrict__ d1,
    const int* __restrict__ d2, int* __restrict__ deg, int E, int N) {
  int e = blockIdx.x * 256 + threadIdx.x;
  if (e < 2 * E) {
    int g = e >= E;
    int le = g ? e - E : e;
    int d = g ? d2[le] : d1[le];
    atomicAdd(&deg[g * N + d], 1);
  }
}

__global__ __launch_bounds__(1024) void scan_part_kernel(const int* __restrict__ deg,
    int* __restrict__ offs, int* __restrict__ partials, int n) {
  __shared__ int wsum[16], wpref[16];
  int tid = threadIdx.x, lane = tid & 63, wid = tid >> 6;
  int idx = blockIdx.x * 1024 + tid;
  int v = (idx < n) ? deg[idx] : 0;
  int s = v;
#pragma unroll
  for (int o = 1; o < 64; o <<= 1) {
    int t = __shfl_up(s, o, 64);
    if (lane >= o) s += t;
  }
  if (lane == 63) wsum[wid] = s;
  __syncthreads();
  if (tid < 16) {
    int t = wsum[tid];
    int ss = t;
#pragma unroll
    for (int o = 1; o < 16; o <<= 1) {
      int u = __shfl_up(ss, o, 16);
      if (tid >= o) ss += u;
    }
    wpref[tid] = ss - t;
    if (tid == 15) partials[blockIdx.x] = ss;
  }
  __syncthreads();
  if (idx < n) offs[idx] = wpref[wid] + s - v;
}

// generalized: block-wide scan of up to 1024 partials; block0 writes total, b>0 adds carry
__global__ __launch_bounds__(1024) void scan_fix_kernel(int* __restrict__ offs,
    const int* __restrict__ partials, int nb, int n) {
  __shared__ int wsum[16], wpref[16];
  __shared__ int carry_s;
  int tid = threadIdx.x, lane = tid & 63, wid = tid >> 6;
  int v = (tid < nb) ? partials[tid] : 0;
  int s = v;
#pragma unroll
  for (int o = 1; o < 64; o <<= 1) {
    int t = __shfl_up(s, o, 64);
    if (lane >= o) s += t;
  }
  if (lane == 63) wsum[wid] = s;
  __syncthreads();
  if (tid < 16) {
    int t = wsum[tid];
    int ss = t;
#pragma unroll
    for (int o = 1; o < 16; o <<= 1) {
      int u = __shfl_up(ss, o, 16);
      if (tid >= o) ss += u;
    }
    wpref[tid] = ss - t;
  }
  __syncthreads();
  s += wpref[wid];                     // inclusive scan of partials
  int b = blockIdx.x;
  if (b == 0) {
    if (tid == nb - 1) offs[n] = s;
  } else if (tid == b - 1) {
    carry_s = s;
  }
  __syncthreads();
  if (b > 0) {
    int idx = b * 1024 + tid;
    if (idx < n) offs[idx] += carry_s;
  }
}

__global__ __launch_bounds__(256) void fill_kernel(const int* __restrict__ ei1,
    const int* __restrict__ ei2, const int* __restrict__ offs,
    int* __restrict__ cnt, int* __restrict__ csr, int E, int N) {
  int e = blockIdx.x * 256 + threadIdx.x;
  if (e < 2 * E) {
    int g = e >= E;
    int le = g ? e - E : e;
    const int* ei = g ? ei2 : ei1;
    int sN = ei[le];
    int d  = ei[le + E];
    int node = g * N + d;
    int pos = offs[node] + atomicAdd(&cnt[node], 1);
    csr[pos] = g * N + sN;            // global source id
  }
}

// ---------------- weight converts (tiny, once) ----------------
__global__ __launch_bounds__(256) void cvt_w_kernel(const float* __restrict__ Wl,
    const float* __restrict__ Wr, unsigned short* __restrict__ Wt) {
  int n = blockIdx.x;
  int k = threadIdx.x;
  float v = (n < 256) ? Wl[k * 256 + n] : Wr[k * 256 + (n - 256)];
  Wt[n * 256 + k] = f2bf(v);
}

__global__ __launch_bounds__(256) void cvt_w2_kernel(const float* __restrict__ Wl,
    const float* __restrict__ Wr, unsigned short* __restrict__ Wt2) {
  int c = blockIdx.x;
  int k = threadIdx.x;
  float v = (c < 16) ? Wl[k * 16 + c] : Wr[k * 16 + (c - 16)];
  Wt2[c * 256 + k] = f2bf(v);
}

// ---------------- MFMA GEMM: M=2N rows (x1|x2), 128x128 tile, 8 waves, BK=64 ----------------
// outputs split: cols 0..255 -> xlb, 256..511 -> xrb (uniform per block)
#define LDT 72
__global__ __launch_bounds__(512) void gemm_mfma_kernel(
    const float* __restrict__ X1, const float* __restrict__ X2,
    const unsigned short* __restrict__ Bt,
    unsigned short* __restrict__ xlb, unsigned short* __restrict__ xrb,
    int M, int NN) {
  __shared__ __align__(16) unsigned short As[128 * LDT];
  __shared__ __align__(16) unsigned short Bs[128 * LDT];
  int tid = threadIdx.x;
  int G = gridDim.x;
  int q = G >> 3, r = G & 7;
  int b = blockIdx.x;
  int xcd = b & 7, pos = b >> 3;
  int swz = (xcd < r) ? xcd * (q + 1) + pos : r * (q + 1) + (xcd - r) * q + pos;
  int row0 = (swz >> 2) * 128;
  int col0 = (swz & 3) * 128;
  int wid = tid >> 6, lane = tid & 63;
  int wr = wid >> 2, wc = wid & 3;          // 2x4 wave grid; wave = 64r x 32c
  int r16 = lane & 15, kb = (lane >> 4) * 8;

  f32x4v acc[4][2];
#pragma unroll
  for (int m = 0; m < 4; m++)
#pragma unroll
    for (int n = 0; n < 2; n++)
#pragma unroll
      for (int qq = 0; qq < 4; qq++) acc[m][n][qq] = 0.f;

  for (int k0 = 0; k0 < 256; k0 += 64) {
#pragma unroll
    for (int it = 0; it < 2; it++) {
      int g = tid + it * 512;         // 0..1023 granules of 8 elems
      int rr = g >> 3;
      int ko = (g & 7) * 8;
      int gr = row0 + rr;
      float4 a0 = make_float4(0.f, 0.f, 0.f, 0.f);
      float4 a1 = make_float4(0.f, 0.f, 0.f, 0.f);
      if (gr < M) {
        const float* src = (gr < NN) ? &X1[(size_t)gr * 256]
                                     : &X2[(size_t)(gr - NN) * 256];
        a0 = *(const float4*)&src[k0 + ko];
        a1 = *(const float4*)&src[k0 + ko + 4];
      }
      ushort4 lo, hi;
      lo.x = f2bf(a0.x); lo.y = f2bf(a0.y); lo.z = f2bf(a0.z); lo.w = f2bf(a0.w);
      hi.x = f2bf(a1.x); hi.y = f2bf(a1.y); hi.z = f2bf(a1.z); hi.w = f2bf(a1.w);
      *(ushort4*)&As[rr * LDT + ko] = lo;
      *(ushort4*)&As[rr * LDT + ko + 4] = hi;
      int4 bv = *(const int4*)&Bt[(size_t)(col0 + rr) * 256 + k0 + ko];
      *(int4*)&Bs[rr * LDT + ko] = bv;
    }
    __syncthreads();
#pragma unroll
    for (int kk = 0; kk < 64; kk += 32) {
      bf16x8 af[4], bfr[2];
#pragma unroll
      for (int m = 0; m < 4; m++)
        af[m] = *(const bf16x8*)&As[(wr * 64 + m * 16 + r16) * LDT + kk + kb];
#pragma unroll
      for (int n = 0; n < 2; n++)
        bfr[n] = *(const bf16x8*)&Bs[(wc * 32 + n * 16 + r16) * LDT + kk + kb];
#pragma unroll
      for (int m = 0; m < 4; m++)
#pragma unroll
        for (int n = 0; n < 2; n++)
          acc[m][n] = __builtin_amdgcn_mfma_f32_16x16x32_bf16(af[m], bfr[n], acc[m][n], 0, 0, 0);
    }
    __syncthreads();
  }
  unsigned short* Cb = (col0 < 256) ? xlb : xrb;
  int cbase = (col0 & 255) + wc * 32;
  int rq = (lane >> 4) * 4;
#pragma unroll
  for (int m = 0; m < 4; m++) {
#pragma unroll
    for (int n = 0; n < 2; n++) {
#pragma unroll
      for (int qq = 0; qq < 4; qq++) {
        int gr = row0 + wr * 64 + m * 16 + rq + qq;
        if (gr < M) {
          Cb[(size_t)gr * 256 + cbase + n * 16 + r16] = f2bf(acc[m][n][qq]);
        }
      }
    }
  }
}

// ---------------- layer-2 MFMA GEMM: [M,32] = h[M,256] @ Wt2^T, split xl2/xr2 ----------------
#define LDB2 264
__global__ __launch_bounds__(256) void gemm2_mfma_kernel(
    const unsigned short* __restrict__ A, const unsigned short* __restrict__ Bt,
    unsigned short* __restrict__ xl2b, unsigned short* __restrict__ xr2b, int M) {
  __shared__ __align__(16) unsigned short As[256 * LDT];
  __shared__ __align__(16) unsigned short Bs[32 * LDB2];
  int tid = threadIdx.x;
  int row0 = blockIdx.x * 256;
  int wid = tid >> 6, lane = tid & 63;
  int r16 = lane & 15, kb = (lane >> 4) * 8, rq = (lane >> 4) * 4;

#pragma unroll
  for (int it = 0; it < 4; it++) {
    int g = tid + it * 256;
    int rr = g >> 5;
    int ko = (g & 31) * 8;
    *(int4*)&Bs[rr * LDB2 + ko] = *(const int4*)&Bt[rr * 256 + ko];
  }

  f32x4v acc[4][2];
#pragma unroll
  for (int m = 0; m < 4; m++)
#pragma unroll
    for (int n = 0; n < 2; n++)
#pragma unroll
      for (int qq = 0; qq < 4; qq++) acc[m][n][qq] = 0.f;

  for (int k0 = 0; k0 < 256; k0 += 64) {
#pragma unroll
    for (int it = 0; it < 8; it++) {
      int g = tid + it * 256;
      int rr = g >> 3;
      int ko = (g & 7) * 8;
      int gr = row0 + rr;
      int4 av = make_int4(0, 0, 0, 0);
      if (gr < M) av = *(const int4*)&A[(size_t)gr * 256 + k0 + ko];
      *(int4*)&As[rr * LDT + ko] = av;
    }
    __syncthreads();
#pragma unroll
    for (int kk = 0; kk < 64; kk += 32) {
      bf16x8 af[4], bfr[2];
#pragma unroll
      for (int m = 0; m < 4; m++)
        af[m] = *(const bf16x8*)&As[(wid * 64 + m * 16 + r16) * LDT + kk + kb];
#pragma unroll
      for (int n = 0; n < 2; n++)
        bfr[n] = *(const bf16x8*)&Bs[(n * 16 + r16) * LDB2 + k0 + kk + kb];
#pragma unroll
      for (int m = 0; m < 4; m++)
#pragma unroll
        for (int n = 0; n < 2; n++)
          acc[m][n] = __builtin_amdgcn_mfma_f32_16x16x32_bf16(af[m], bfr[n], acc[m][n], 0, 0, 0);
    }
    __syncthreads();
  }
#pragma unroll
  for (int m = 0; m < 4; m++) {
#pragma unroll
    for (int qq = 0; qq < 4; qq++) {
      int gr = row0 + wid * 64 + m * 16 + rq + qq;
      if (gr < M) {
        xl2b[(size_t)gr * 16 + r16] = f2bf(acc[m][0][qq]);
        xr2b[(size_t)gr * 16 + r16] = f2bf(acc[m][1][qq]);
      }
    }
  }
}

// ---------------- fused GATv2 layer 1 (1 wave/node over 2N, depth-3 prefetch) ----------------
// h is written into xrb (alias-safe: block i reads only xr[i] before writing h[i]).
__global__ __launch_bounds__(256) void gat1_kernel(const unsigned short* __restrict__ xlb,
    unsigned short* xrb, const float* __restrict__ att, const float* __restrict__ bias,
    const int* __restrict__ offs, const int* __restrict__ csr, int M) {
  int w = threadIdx.x >> 6, lane = threadIdx.x & 63;
  int i = blockIdx.x * 4 + w;
  if (i >= M) return;
  i = __builtin_amdgcn_readfirstlane(i);
  const uint2* rows = (const uint2*)xlb;    // 64 x 8B per row
  uint2 ul = rows[(size_t)i * 64 + lane];
  uint2 ur = ((const uint2*)(xrb + (size_t)i * 256))[lane];
  f32x2 xl01 = bfpair(ul.x), xl23 = bfpair(ul.y);
  f32x2 xr01 = bfpair(ur.x), xr23 = bfpair(ur.y);
  float4 a4 = ((const float4*)att)[lane];
  f32x2 a01; a01.x = a4.x; a01.y = a4.y;
  f32x2 a23; a23.x = a4.z; a23.y = a4.w;

  f32x2 t01 = xl01 + xr01, t23 = xl23 + xr23;
  f32x2 l01 = __builtin_elementwise_max(t01, t01 * NEG);
  f32x2 l23 = __builtin_elementwise_max(t23, t23 * NEG);
  f32x2 ps = l01 * a01 + l23 * a23;
  float p = ps.x + ps.y;
  p += __shfl_xor(p, 1, 8);
  p += __shfl_xor(p, 2, 8);
  p += __shfl_xor(p, 4, 8);
  float m = p, ssum = 1.f;
  f32x2 O01 = xl01, O23 = xl23;

  int e = offs[i], end = offs[i + 1];
  int rem = end - e;

  int ja0 = __builtin_amdgcn_readfirstlane(rem > 0 ? csr[e + 0] : i);
  int ja1 = __builtin_amdgcn_readfirstlane(rem > 1 ? csr[e + 1] : i);
  uint2 ua0 = rows[(size_t)ja0 * 64 + lane];
  uint2 ua1 = rows[(size_t)ja1 * 64 + lane];
  int jb0 = __builtin_amdgcn_readfirstlane(rem > 2 ? csr[e + 2] : i);
  int jb1 = __builtin_amdgcn_readfirstlane(rem > 3 ? csr[e + 3] : i);
  uint2 ub0 = rows[(size_t)jb0 * 64 + lane];
  uint2 ub1 = rows[(size_t)jb1 * 64 + lane];
  int jc0 = __builtin_amdgcn_readfirstlane(rem > 4 ? csr[e + 4] : i);
  int jc1 = __builtin_amdgcn_readfirstlane(rem > 5 ? csr[e + 5] : i);
  uint2 uc0 = rows[(size_t)jc0 * 64 + lane];
  uint2 uc1 = rows[(size_t)jc1 * 64 + lane];

  while (rem >= 2) {
    int jn0 = __builtin_amdgcn_readfirstlane(rem > 6 ? csr[e + 6] : i);
    int jn1 = __builtin_amdgcn_readfirstlane(rem > 7 ? csr[e + 7] : i);
    uint2 un0 = rows[(size_t)jn0 * 64 + lane];
    uint2 un1 = rows[(size_t)jn1 * 64 + lane];
    f32x2 x001 = bfpair(ua0.x), x023 = bfpair(ua0.y);
    f32x2 x101 = bfpair(ua1.x), x123 = bfpair(ua1.y);
    f32x2 q01 = x001 + xr01, q23 = x023 + xr23;
    f32x2 r01 = x101 + xr01, r23 = x123 + xr23;
    f32x2 g01 = __builtin_elementwise_max(q01, q01 * NEG);
    f32x2 g23 = __builtin_elementwise_max(q23, q23 * NEG);
    f32x2 k01 = __builtin_elementwise_max(r01, r01 * NEG);
    f32x2 k23 = __builtin_elementwise_max(r23, r23 * NEG);
    f32x2 s0v = g01 * a01 + g23 * a23;
    f32x2 s1v = k01 * a01 + k23 * a23;
    float p0 = s0v.x + s0v.y;
    float p1 = s1v.x + s1v.y;
    p0 += __shfl_xor(p0, 1, 8);
    p1 += __shfl_xor(p1, 1, 8);
    p0 += __shfl_xor(p0, 2, 8);
    p1 += __shfl_xor(p1, 2, 8);
    p0 += __shfl_xor(p0, 4, 8);
    p1 += __shfl_xor(p1, 4, 8);
    float mx = fmaxf(p0, p1);
    if (!__all(mx <= m + 8.f)) {        // defer-max (T13)
      float mn = fmaxf(m, mx);
      float sc = __expf(m - mn);
      O01 *= sc; O23 *= sc; ssum *= sc; m = mn;
    }
    float w0 = __expf(p0 - m), w1 = __expf(p1 - m);
    O01 += w0 * x001 + w1 * x101;
    O23 += w0 * x023 + w1 * x123;
    ssum += w0 + w1;
    ua0 = ub0; ua1 = ub1;
    ub0 = uc0; ub1 = uc1;
    uc0 = un0; uc1 = un1;
    e += 2; rem -= 2;
  }
  if (rem == 1) {
    f32x2 x001 = bfpair(ua0.x), x023 = bfpair(ua0.y);
    f32x2 q01 = x001 + xr01, q23 = x023 + xr23;
    f32x2 g01 = __builtin_elementwise_max(q01, q01 * NEG);
    f32x2 g23 = __builtin_elementwise_max(q23, q23 * NEG);
    f32x2 s0v = g01 * a01 + g23 * a23;
    float p0 = s0v.x + s0v.y;
    p0 += __shfl_xor(p0, 1, 8);
    p0 += __shfl_xor(p0, 2, 8);
    p0 += __shfl_xor(p0, 4, 8);
    if (!__all(p0 <= m + 8.f)) {
      float mn = fmaxf(m, p0);
      float sc = __expf(m - mn);
      O01 *= sc; O23 *= sc; ssum *= sc; m = mn;
    }
    float w0 = __expf(p0 - m);
    O01 += w0 * x001;
    O23 += w0 * x023;
    ssum += w0;
  }
  float inv = 1.f / (ssum + 1e-16f);
  float4 b4 = ((const float4*)bias)[lane];
  float h0 = O01.x * inv + b4.x;
  float h1 = O01.y * inv + b4.y;
  float h2 = O23.x * inv + b4.z;
  float h3 = O23.y * inv + b4.w;
  h0 = h0 > 0.f ? h0 : (__expf(h0) - 1.f);
  h1 = h1 > 0.f ? h1 : (__expf(h1) - 1.f);
  h2 = h2 > 0.f ? h2 : (__expf(h2) - 1.f);
  h3 = h3 > 0.f ? h3 : (__expf(h3) - 1.f);
  ushort4 o;
  o.x = f2bf(h0); o.y = f2bf(h1); o.z = f2bf(h2); o.w = f2bf(h3);
  ((ushort4*)(xrb + (size_t)i * 256))[lane] = o;   // h aliases xr (own row only)
}

// ---------------- fused GATv2 layer 2 (2N nodes, bf16 split arrays) ----------------
__global__ __launch_bounds__(256) void gat2_kernel(const unsigned short* __restrict__ xl2b,
    const unsigned short* __restrict__ xr2b, const float* __restrict__ att,
    const float* __restrict__ b2, const int* __restrict__ offs,
    const int* __restrict__ csr, float* __restrict__ y2, int M) {
  int grp = threadIdx.x >> 4, c = threadIdx.x & 15;
  int i = blockIdx.x * 16 + grp;
  if (i >= M) return;
  float xli = bf2f(xl2b[(size_t)i * 16 + c]);
  float xri = bf2f(xr2b[(size_t)i * 16 + c]);
  float a = att[c];
  float v = xli + xri; v = fmaxf(v, NEG * v);
  float p = v * a;
#pragma unroll
  for (int o = 8; o >= 1; o >>= 1) p += __shfl_xor(p, o, 16);
  float m = p, ssum = 1.0f, O = xli;

  int e = offs[i], end = offs[i + 1];
  int rem = end - e;

  int ja0 = rem > 0 ? csr[e + 0] : i;
  int ja1 = rem > 1 ? csr[e + 1] : i;
  float xa0 = bf2f(xl2b[(size_t)ja0 * 16 + c]);
  float xa1 = bf2f(xl2b[(size_t)ja1 * 16 + c]);
  int jb0 = rem > 2 ? csr[e + 2] : i;
  int jb1 = rem > 3 ? csr[e + 3] : i;
  float xb0 = bf2f(xl2b[(size_t)jb0 * 16 + c]);
  float xb1 = bf2f(xl2b[(size_t)jb1 * 16 + c]);
  int jc0 = rem > 4 ? csr[e + 4] : i;
  int jc1 = rem > 5 ? csr[e + 5] : i;
  float xc0 = bf2f(xl2b[(size_t)jc0 * 16 + c]);
  float xc1 = bf2f(xl2b[(size_t)jc1 * 16 + c]);

  while (rem >= 2) {
    int jn0 = rem > 6 ? csr[e + 6] : i;
    int jn1 = rem > 7 ? csr[e + 7] : i;
    float xn0 = bf2f(xl2b[(size_t)jn0 * 16 + c]);
    float xn1 = bf2f(xl2b[(size_t)jn1 * 16 + c]);
    float q0 = xa0 + xri; q0 = fmaxf(q0, NEG * q0);
    float q1 = xa1 + xri; q1 = fmaxf(q1, NEG * q1);
    float p0 = q0 * a, p1 = q1 * a;
#pragma unroll
    for (int o = 8; o >= 1; o >>= 1) {
      p0 += __shfl_xor(p0, o, 16);
      p1 += __shfl_xor(p1, o, 16);
    }
    float mx = fmaxf(p0, p1);
    if (!__all(mx <= m + 8.f)) {
      float mn = fmaxf(m, mx);
      float sc = __expf(m - mn);
      O *= sc; ssum *= sc; m = mn;
    }
    float w0 = __expf(p0 - m), w1 = __expf(p1 - m);
    O += w0 * xa0 + w1 * xa1;
    ssum += w0 + w1;
    xa0 = xb0; xa1 = xb1;
    xb0 = xc0; xb1 = xc1;
    xc0 = xn0; xc1 = xn1;
    e += 2; rem -= 2;
  }
  if (rem == 1) {
    float q0 = xa0 + xri; q0 = fmaxf(q0, NEG * q0);
    float p0 = q0 * a;
#pragma unroll
    for (int o = 8; o >= 1; o >>= 1) p0 += __shfl_xor(p0, o, 16);
    if (!__all(p0 <= m + 8.f)) {
      float mn = fmaxf(m, p0);
      float sc = __expf(m - mn);
      O *= sc; ssum *= sc; m = mn;
    }
    float w0 = __expf(p0 - m);
    O += w0 * xa0;
    ssum += w0;
  }
  y2[(size_t)i * C2 + c] = O / (ssum + 1e-16f) + b2[c];
}

// ---------------- finalize ----------------
__global__ __launch_bounds__(256) void finalize_kernel(const float* __restrict__ y,
    const float* __restrict__ z, float* __restrict__ out, int N) {
  int grp = threadIdx.x >> 4, c = threadIdx.x & 15;
  int i = blockIdx.x * 16 + grp;
  if (i >= N) return;
  float yv = y[(size_t)i * C2 + c];
  float zv = z[(size_t)i * C2 + c];
  float my = yv;
#pragma unroll
  for (int o = 8; o >= 1; o >>= 1) my = fmaxf(my, __shfl_xor(my, o, 16));
  float sy = __expf(yv - my);
#pragma unroll
  for (int o = 8; o >= 1; o >>= 1) sy += __shfl_xor(sy, o, 16);
  float lpy = yv - my - __logf(sy);
  float mz = zv;
#pragma unroll
  for (int o = 8; o >= 1; o >>= 1) mz = fmaxf(mz, __shfl_xor(mz, o, 16));
  float sz = __expf(zv - mz);
#pragma unroll
  for (int o = 8; o >= 1; o >>= 1) sz += __shfl_xor(sz, o, 16);
  float lpz = zv - mz - __logf(sz);
  float dot = yv * zv, ny2 = yv * yv, nz2 = zv * zv;
#pragma unroll
  for (int o = 8; o >= 1; o >>= 1) {
    dot += __shfl_xor(dot, o, 16);
    ny2 += __shfl_xor(ny2, o, 16);
    nz2 += __shfl_xor(nz2, o, 16);
  }
  float ny = fmaxf(sqrtf(ny2), 1e-8f);
  float nz = fmaxf(sqrtf(nz2), 1e-8f);
  float cosv = dot / (ny * nz);
  size_t o1 = (size_t)N * C2;
  size_t o2 = o1 + N;
  size_t o3 = o2 + (size_t)N * C2;
  size_t o4 = o3 + (size_t)N * C2;
  size_t idx = (size_t)i * C2 + c;
  out[idx] = lpy;
  if (c == 0) out[o1 + i] = 1.0f - cosv;
  out[o2 + idx] = lpz;
  out[o3 + idx] = lpy;
  out[o4 + idx] = lpy;
}

extern "C" void kernel_launch(void* const* d_in, const int* in_sizes, int n_in,
                              void* d_out, int out_size, void* d_ws, size_t ws_size,
                              hipStream_t stream) {
  const float* x1   = (const float*)d_in[0];
  const int*   ei1  = (const int*)d_in[1];
  const float* x2   = (const float*)d_in[2];
  const int*   ei2  = (const int*)d_in[3];
  const float* W1l  = (const float*)d_in[4];
  const float* W1r  = (const float*)d_in[5];
  const float* att1 = (const float*)d_in[6];
  const float* b1   = (const float*)d_in[7];
  const float* W2l  = (const float*)d_in[8];
  const float* W2r  = (const float*)d_in[9];
  const float* att2 = (const float*)d_in[10];
  const float* b2   = (const float*)d_in[11];
  const int N = in_sizes[0] / FIN;
  const int E = in_sizes[1] / 2;
  const int M = 2 * N;                 // merged node count
  float* out = (float*)d_out;

  char* w = (char*)d_ws;
  size_t off = 0;
  auto carve = [&](size_t bytes) -> void* {
    void* p = w + off;
    off += (bytes + 255) & ~(size_t)255;
    return p;
  };
  unsigned short* xlb  = (unsigned short*)carve((size_t)M * 256 * 2);
  unsigned short* xrb  = (unsigned short*)carve((size_t)M * 256 * 2);  // xr, then h (alias)
  unsigned short* Wt   = (unsigned short*)carve(512 * 256 * 2);
  unsigned short* Wt2  = (unsigned short*)carve(32 * 256 * 2);
  unsigned short* xl2b = (unsigned short*)carve((size_t)M * 16 * 2);
  unsigned short* xr2b = (unsigned short*)carve((size_t)M * 16 * 2);
  float* y2  = (float*)carve((size_t)M * 16 * 4);                      // y | z
  int* deg  = (int*)carve((size_t)M * 4);
  int* cnt  = (int*)carve((size_t)M * 4);
  int* offs = (int*)carve((size_t)(M + 1) * 4);
  int* csr  = (int*)carve((size_t)2 * E * 4);
  int* partials = (int*)carve(128 * 4);
  (void)ws_size; (void)n_in; (void)out_size;

  // one memset spanning deg..cnt (incl. carve padding)
  const size_t zero_bytes = (size_t)((char*)cnt - (char*)deg) + (size_t)M * 4;
  hipMemsetAsync(deg, 0, zero_bytes, stream);

  const int NB = (M + 1023) / 1024;    // 98 (<=1024 required by scan_fix)

  cvt_w_kernel<<<512, 256, 0, stream>>>(W1l, W1r, Wt);
  cvt_w2_kernel<<<32, 256, 0, stream>>>(W2l, W2r, Wt2);

  // CSR for both graphs in one pass
  deg_kernel<<<(2 * E + 255) / 256, 256, 0, stream>>>(ei1 + E, ei2 + E, deg, E, N);
  scan_part_kernel<<<NB, 1024, 0, stream>>>(deg, offs, partials, M);
  scan_fix_kernel<<<NB, 1024, 0, stream>>>(offs, partials, NB, M);
  fill_kernel<<<(2 * E + 255) / 256, 256, 0, stream>>>(ei1, ei2, offs, cnt, csr, E, N);

  // both graphs' layer-1 GEMM in one dispatch
  int RB = (M + 127) / 128;
  gemm_mfma_kernel<<<RB * 4, 512, 0, stream>>>(x1, x2, Wt, xlb, xrb, M, N);
  gat1_kernel<<<(M + 3) / 4, 256, 0, stream>>>(xlb, xrb, att1, b1, offs, csr, M);
  gemm2_mfma_kernel<<<(M + 255) / 256, 256, 0, stream>>>(xrb, Wt2, xl2b, xr2b, M);
  gat2_kernel<<<(M + 15) / 16, 256, 0, stream>>>(xl2b, xr2b, att2, b2, offs, csr, y2, M);

  finalize_kernel<<<(N + 15) / 16, 256, 0, stream>>>(y2, y2 + (size_t)N * 16, out, N);
}